// Round 1
// baseline (111.682 us; speedup 1.0000x reference)
//
#include <hip/hip_runtime.h>
#include <math.h>

// out[b,s,e] = sum_q cos(x[b,s,q] + theta[q]) * W[e,q]
// B=4, S=4096, E=1024, Q=8  -> tokens = 16384
// Traffic floor: 67 MB output write (+0.5 MB of x touched) ~ 11 us at 6.5 TB/s
// measured write ceiling (fillBuffer dispatches run 268 MB at 41 us = 6.5 TB/s).

#define E_DIM 1024
#define Q_DIM 8
#define TPB 256
#define TOK_PER_BLOCK 8   // 2048 blocks -> 8 blocks/CU, 32 waves/CU

typedef float f32x4 __attribute__((ext_vector_type(4)));

__global__ __launch_bounds__(TPB) void quantum_proj_kernel(
    const float* __restrict__ x,      // [tokens, 1024]
    const float* __restrict__ theta,  // [8]
    const float* __restrict__ W,      // [1024, 8]
    float* __restrict__ out,          // [tokens, 1024]
    int tokens)
{
    __shared__ float P[TOK_PER_BLOCK * Q_DIM];   // 256 B

    const int t    = threadIdx.x;
    const int tok0 = blockIdx.x * TOK_PER_BLOCK;

    // ---- Phase 1: first wave computes cos(x[tok][q] + theta[q]) into LDS.
    // 8 tokens x 8 qubits = 64 lanes, one scalar load + cosf each.
    if (t < TOK_PER_BLOCK * Q_DIM) {
        const int tl  = t >> 3;    // local token
        const int q   = t & 7;
        const int tok = tok0 + tl;
        float v = 0.0f;
        if (tok < tokens) {
            v = cosf(x[(size_t)tok * E_DIM + q] + theta[q]);
        }
        P[t] = v;
    }

    // ---- Each thread owns output columns e = 4t .. 4t+3: load its 4 W rows
    // (32 contiguous floats = bytes [128t, 128t+128), fully coalesced, L2-hot).
    const int e0 = t * 4;
    float w[4][Q_DIM];
    {
        const float4* W4 = (const float4*)W;
        #pragma unroll
        for (int i = 0; i < 4; ++i) {
            float4 a = W4[(size_t)(e0 + i) * 2 + 0];
            float4 b = W4[(size_t)(e0 + i) * 2 + 1];
            w[i][0] = a.x; w[i][1] = a.y; w[i][2] = a.z; w[i][3] = a.w;
            w[i][4] = b.x; w[i][5] = b.y; w[i][6] = b.z; w[i][7] = b.w;
        }
    }

    __syncthreads();

    // ---- Phase 2: per token, 32 FMAs + one 16 B non-temporal store.
    // Wave stores 1 KB contiguous; block covers the full 4 KB row per token.
    #pragma unroll
    for (int tl = 0; tl < TOK_PER_BLOCK; ++tl) {
        const int tok = tok0 + tl;
        if (tok >= tokens) break;

        float p[Q_DIM];
        #pragma unroll
        for (int q = 0; q < Q_DIM; ++q) p[q] = P[tl * Q_DIM + q];  // LDS broadcast

        f32x4 acc = {0.f, 0.f, 0.f, 0.f};
        #pragma unroll
        for (int i = 0; i < 4; ++i) {
            #pragma unroll
            for (int q = 0; q < Q_DIM; ++q) {
                acc[i] = fmaf(p[q], w[i][q], acc[i]);
            }
        }

        // Output is write-once, never re-read: bypass L2 allocate.
        __builtin_nontemporal_store(acc, (f32x4*)(out + (size_t)tok * E_DIM) + t);
    }
}

extern "C" void kernel_launch(void* const* d_in, const int* in_sizes, int n_in,
                              void* d_out, int out_size, void* d_ws, size_t ws_size,
                              hipStream_t stream) {
    const float* x     = (const float*)d_in[0];
    const float* theta = (const float*)d_in[1];
    const float* W     = (const float*)d_in[2];
    float* out = (float*)d_out;

    const int tokens = in_sizes[0] / E_DIM;                           // 16384
    const int grid   = (tokens + TOK_PER_BLOCK - 1) / TOK_PER_BLOCK;  // 2048

    quantum_proj_kernel<<<dim3(grid), dim3(TPB), 0, stream>>>(x, theta, W, out, tokens);
}